// Round 1
// baseline (258.101 us; speedup 1.0000x reference)
//
#include <hip/hip_runtime.h>
#include <hip/hip_bf16.h>

#define B_ 2
#define S_ 4096
#define DM 512
#define NH 8
#define DK 64

typedef __bf16 bf16;
typedef __attribute__((ext_vector_type(8))) __bf16 bf16x8;
typedef __attribute__((ext_vector_type(4))) __bf16 bf16x4;
typedef __attribute__((ext_vector_type(4))) float f32x4;

// Stage 16 consecutive fp32 -> 16 bf16 into a 128B LDS row with XOR block swizzle.
// half selects which 32B half of the 64B data region; blocks are 16B, swizzled ^ (r&7).
__device__ __forceinline__ void stage16f(const float* __restrict__ src,
                                         bf16* __restrict__ row, int half, int r) {
  const f32x4* s4 = (const f32x4*)src;
  f32x4 f0 = s4[0], f1 = s4[1], f2 = s4[2], f3 = s4[3];
  bf16x8 h0, h1;
#pragma unroll
  for (int i = 0; i < 4; ++i) {
    h0[i]     = (__bf16)f0[i];
    h0[4 + i] = (__bf16)f1[i];
    h1[i]     = (__bf16)f2[i];
    h1[4 + i] = (__bf16)f3[i];
  }
  *(bf16x8*)(row + ((((half * 2)    ) ^ (r & 7)) << 3)) = h0;
  *(bf16x8*)(row + ((((half * 2) + 1) ^ (r & 7)) << 3)) = h1;
}

// ---------------- input projections: Q/K/V = X @ W^T + b (bf16 out) ----------------
__global__ __launch_bounds__(256) void proj_in(
    const float* __restrict__ q, const float* __restrict__ k, const float* __restrict__ v,
    const float* __restrict__ Wq, const float* __restrict__ bq,
    const float* __restrict__ Wk, const float* __restrict__ bk,
    const float* __restrict__ Wv, const float* __restrict__ bv,
    bf16* __restrict__ Qh, bf16* __restrict__ Kh, bf16* __restrict__ Vt) {
  __shared__ bf16 Ash[128][64];
  __shared__ bf16 Bsh[128][64];

  const int mode = blockIdx.z;
  const float* X    = (mode == 0) ? q  : (mode == 1) ? k  : v;
  const float* W    = (mode == 0) ? Wq : (mode == 1) ? Wk : Wv;
  const float* bias = (mode == 0) ? bq : (mode == 1) ? bk : bv;

  const int t = threadIdx.x, wid = t >> 6, lane = t & 63;
  const int g = lane >> 4, lr = lane & 15;
  const int tileM = blockIdx.x * 128, tileN = blockIdx.y * 128;
  const int wr = (wid >> 1) * 64, wc = (wid & 1) * 64;
  const int sr = t >> 1, sc = (t & 1) * 16;

  f32x4 acc[4][4] = {};

  for (int k0 = 0; k0 < DM; k0 += 32) {
    stage16f(X + (size_t)(tileM + sr) * DM + k0 + sc, &Ash[sr][0], t & 1, sr);
    stage16f(W + (size_t)(tileN + sr) * DM + k0 + sc, &Bsh[sr][0], t & 1, sr);
    __syncthreads();
    bf16x8 af[4], bfr[4];
#pragma unroll
    for (int i = 0; i < 4; ++i) {
      int ra = wr + i * 16 + lr;
      af[i]  = *(const bf16x8*)(&Ash[ra][(g ^ (ra & 7)) << 3]);
      int rb = wc + i * 16 + lr;
      bfr[i] = *(const bf16x8*)(&Bsh[rb][(g ^ (rb & 7)) << 3]);
    }
#pragma unroll
    for (int i = 0; i < 4; ++i)
#pragma unroll
      for (int j = 0; j < 4; ++j)
        acc[i][j] = __builtin_amdgcn_mfma_f32_16x16x32_bf16(af[i], bfr[j], acc[i][j], 0, 0, 0);
    __syncthreads();
  }

  const float scale = (mode == 0) ? 0.125f : 1.0f;  // fold 1/sqrt(64) into Q
#pragma unroll
  for (int j = 0; j < 4; ++j) {
    int n = tileN + wc + j * 16 + lr;
    float bv_ = bias[n];
    int h = n >> 6, d = n & 63;
#pragma unroll
    for (int i = 0; i < 4; ++i) {
#pragma unroll
      for (int r = 0; r < 4; ++r) {
        int m = tileM + wr + i * 16 + g * 4 + r;
        int b = m >> 12, s = m & (S_ - 1);
        bf16 val = (__bf16)((acc[i][j][r] + bv_) * scale);
        if (mode == 2)
          Vt[((size_t)(b * NH + h) * DK + d) * S_ + s] = val;            // [b][h][d][s]
        else if (mode == 0)
          Qh[(((size_t)(b * NH + h) * S_ + s) << 6) + d] = val;          // [b][h][s][d]
        else
          Kh[(((size_t)(b * NH + h) * S_ + s) << 6) + d] = val;
      }
    }
  }
}

// ---------------- flash attention: O = softmax(Q K^T) V  (per b,h) ----------------
__global__ __launch_bounds__(256) void attn_kernel(
    const bf16* __restrict__ Qh, const bf16* __restrict__ Kh,
    const bf16* __restrict__ Vt, bf16* __restrict__ O) {
  __shared__ bf16 Klds[32][64];      // 32 kv x 64 d, swizzled 16B blocks
  __shared__ bf16 Vlds[64][64];      // 64 dv x (32 kv data, padded), swizzled
  __shared__ bf16 Plds[4][32][64];   // per-wave P: 32 q x (32 kv data, padded), swizzled

  const int t = threadIdx.x, wid = t >> 6, lane = t & 63;
  const int g = lane >> 4, lr = lane & 15;
  const int bh = blockIdx.y;
  const int q0 = blockIdx.x * 128 + wid * 32;

  const bf16* Qb = Qh + ((size_t)bh * S_ + q0) * DK;
  const bf16* Kb = Kh + (size_t)bh * S_ * DK;
  const bf16* Vb = Vt + (size_t)bh * DK * S_;

  bf16x8 qf[2][2];
#pragma unroll
  for (int qh = 0; qh < 2; ++qh)
#pragma unroll
    for (int dstep = 0; dstep < 2; ++dstep)
      qf[qh][dstep] = *(const bf16x8*)(Qb + (qh * 16 + lr) * DK + dstep * 32 + g * 8);

  f32x4 oacc[2][4] = {};
  float ms[2] = {-__builtin_inff(), -__builtin_inff()};
  float ls[2] = {0.f, 0.f};

  const int krow = t >> 3, kblk = t & 7;
  const int vrow = t >> 2, vblk = t & 3;

  for (int kv0 = 0; kv0 < S_; kv0 += 32) {
    bf16x8 kstg = *(const bf16x8*)(Kb + (size_t)(kv0 + krow) * DK + kblk * 8);
    bf16x8 vstg = *(const bf16x8*)(Vb + (size_t)vrow * S_ + kv0 + vblk * 8);
    *(bf16x8*)(&Klds[krow][(kblk ^ (krow & 7)) << 3]) = kstg;
    *(bf16x8*)(&Vlds[vrow][(vblk ^ (vrow & 7)) << 3]) = vstg;
    __syncthreads();

    // swapped QK^T: C[i=kv][j=q]  -> per lane: q = qh*16+lr, kv = kvt*16 + 4g + reg
    f32x4 sacc[2][2] = {};
#pragma unroll
    for (int kvt = 0; kvt < 2; ++kvt)
#pragma unroll
      for (int dstep = 0; dstep < 2; ++dstep) {
        int row = kvt * 16 + lr;
        bf16x8 kf = *(const bf16x8*)(&Klds[row][(((dstep * 4 + g) ^ (row & 7)) << 3)]);
#pragma unroll
        for (int qh = 0; qh < 2; ++qh)
          sacc[qh][kvt] = __builtin_amdgcn_mfma_f32_16x16x32_bf16(kf, qf[qh][dstep], sacc[qh][kvt], 0, 0, 0);
      }

#pragma unroll
    for (int qh = 0; qh < 2; ++qh) {
      float lm = fmaxf(fmaxf(fmaxf(sacc[qh][0][0], sacc[qh][0][1]), fmaxf(sacc[qh][0][2], sacc[qh][0][3])),
                       fmaxf(fmaxf(sacc[qh][1][0], sacc[qh][1][1]), fmaxf(sacc[qh][1][2], sacc[qh][1][3])));
      lm = fmaxf(lm, __shfl_xor(lm, 16));
      lm = fmaxf(lm, __shfl_xor(lm, 32));
      float mnew = fmaxf(ms[qh], lm);
      float sf = __expf(ms[qh] - mnew);
      ms[qh] = mnew;
      float p[2][4];
      float rs = 0.f;
#pragma unroll
      for (int kvt = 0; kvt < 2; ++kvt)
#pragma unroll
        for (int r = 0; r < 4; ++r) {
          p[kvt][r] = __expf(sacc[qh][kvt][r] - mnew);
          rs += p[kvt][r];
        }
      rs += __shfl_xor(rs, 16);
      rs += __shfl_xor(rs, 32);
      ls[qh] = ls[qh] * sf + rs;
      // rescale O: owner of q-row x is lane lr==x (within 16-group); our rows are 4g+r
#pragma unroll
      for (int r = 0; r < 4; ++r) {
        float sfr = __shfl(sf, g * 4 + r, 16);
#pragma unroll
        for (int dvt = 0; dvt < 4; ++dvt) oacc[qh][dvt][r] *= sfr;
      }
      // P -> LDS (bf16), row q, 4 consecutive kv per b64 write
      int qq = qh * 16 + lr;
#pragma unroll
      for (int kvt = 0; kvt < 2; ++kvt) {
        bf16x4 pb;
#pragma unroll
        for (int r = 0; r < 4; ++r) pb[r] = (__bf16)p[kvt][r];
        int blk = (kvt * 2 + (g >> 1)) ^ (qq & 7);
        *(bf16x4*)(&Plds[wid][qq][(blk << 3) + ((g & 1) << 2)]) = pb;
      }
    }
    __syncthreads();

    // PV: C[i=q][j=dv]
    bf16x8 pf[2];
#pragma unroll
    for (int qh = 0; qh < 2; ++qh) {
      int row = qh * 16 + lr;
      pf[qh] = *(const bf16x8*)(&Plds[wid][row][(g ^ (row & 7)) << 3]);
    }
#pragma unroll
    for (int dvt = 0; dvt < 4; ++dvt) {
      int row = dvt * 16 + lr;
      bf16x8 vf = *(const bf16x8*)(&Vlds[row][(g ^ (row & 7)) << 3]);
#pragma unroll
      for (int qh = 0; qh < 2; ++qh)
        oacc[qh][dvt] = __builtin_amdgcn_mfma_f32_16x16x32_bf16(pf[qh], vf, oacc[qh][dvt], 0, 0, 0);
    }
    __syncthreads();
  }

  bf16* Ob = O + ((size_t)bh * S_ + q0) * DK;
#pragma unroll
  for (int qh = 0; qh < 2; ++qh) {
    float inv = 1.0f / ls[qh];
#pragma unroll
    for (int r = 0; r < 4; ++r) {
      float invr = __shfl(inv, g * 4 + r, 16);
#pragma unroll
      for (int dvt = 0; dvt < 4; ++dvt)
        Ob[(size_t)(qh * 16 + g * 4 + r) * DK + dvt * 16 + lr] = (__bf16)(oacc[qh][dvt][r] * invr);
    }
  }
}

// ---------------- output projection: out = concat(O) @ Wo^T + bo (fp32 out) ----------------
__global__ __launch_bounds__(256) void proj_out(
    const bf16* __restrict__ O, const float* __restrict__ Wo,
    const float* __restrict__ bo, float* __restrict__ out) {
  __shared__ bf16 Ash[128][64];
  __shared__ bf16 Bsh[128][64];

  const int t = threadIdx.x, wid = t >> 6, lane = t & 63;
  const int g = lane >> 4, lr = lane & 15;
  const int tileM = blockIdx.x * 128, tileN = blockIdx.y * 128;
  const int wr = (wid >> 1) * 64, wc = (wid & 1) * 64;
  const int sr = t >> 1, sc = (t & 1) * 16;

  f32x4 acc[4][4] = {};
  const int m0 = tileM + sr;
  const int bb = m0 >> 12, ss = m0 & (S_ - 1);

  for (int k0 = 0; k0 < DM; k0 += 32) {
    int kk = k0 + sc;
    int h = kk >> 6, d = kk & 63;
    const bf16* srcA = O + (((size_t)(bb * NH + h) * S_ + ss) << 6) + d;
    bf16x8 a0 = *(const bf16x8*)(srcA);
    bf16x8 a1 = *(const bf16x8*)(srcA + 8);
    *(bf16x8*)(&Ash[sr][((((t & 1) * 2)    ) ^ (sr & 7)) << 3]) = a0;
    *(bf16x8*)(&Ash[sr][((((t & 1) * 2) + 1) ^ (sr & 7)) << 3]) = a1;
    stage16f(Wo + (size_t)(tileN + sr) * DM + kk, &Bsh[sr][0], t & 1, sr);
    __syncthreads();
    bf16x8 af[4], bfr[4];
#pragma unroll
    for (int i = 0; i < 4; ++i) {
      int ra = wr + i * 16 + lr;
      af[i]  = *(const bf16x8*)(&Ash[ra][(g ^ (ra & 7)) << 3]);
      int rb = wc + i * 16 + lr;
      bfr[i] = *(const bf16x8*)(&Bsh[rb][(g ^ (rb & 7)) << 3]);
    }
#pragma unroll
    for (int i = 0; i < 4; ++i)
#pragma unroll
      for (int j = 0; j < 4; ++j)
        acc[i][j] = __builtin_amdgcn_mfma_f32_16x16x32_bf16(af[i], bfr[j], acc[i][j], 0, 0, 0);
    __syncthreads();
  }

#pragma unroll
  for (int j = 0; j < 4; ++j) {
    int n = tileN + wc + j * 16 + lr;
    float bias = bo[n];
#pragma unroll
    for (int i = 0; i < 4; ++i) {
#pragma unroll
      for (int r = 0; r < 4; ++r) {
        int m = tileM + wr + i * 16 + g * 4 + r;
        out[(size_t)m * DM + n] = acc[i][j][r] + bias;
      }
    }
  }
}

extern "C" void kernel_launch(void* const* d_in, const int* in_sizes, int n_in,
                              void* d_out, int out_size, void* d_ws, size_t ws_size,
                              hipStream_t stream) {
  const float* q  = (const float*)d_in[0];
  const float* k  = (const float*)d_in[1];
  const float* v  = (const float*)d_in[2];
  const float* Wq = (const float*)d_in[3];
  const float* bq = (const float*)d_in[4];
  const float* Wk = (const float*)d_in[5];
  const float* bk = (const float*)d_in[6];
  const float* Wv = (const float*)d_in[7];
  const float* bv = (const float*)d_in[8];
  const float* Wo = (const float*)d_in[9];
  const float* bo = (const float*)d_in[10];
  float* out = (float*)d_out;

  const size_t perTensor = (size_t)B_ * NH * S_ * DK;  // 4,194,304 elems
  bf16* Qh = (bf16*)d_ws;
  bf16* Kh = Qh + perTensor;
  bf16* Vt = Kh + perTensor;
  bf16* O  = Vt + perTensor;

  proj_in<<<dim3(64, 4, 3), 256, 0, stream>>>(q, k, v, Wq, bq, Wk, bk, Wv, bv, Qh, Kh, Vt);
  attn_kernel<<<dim3(S_ / 128, B_ * NH), 256, 0, stream>>>(Qh, Kh, Vt, O);
  proj_out<<<dim3(64, 4), 256, 0, stream>>>(O, Wo, bo, out);
}

// Round 2
// 175.228 us; speedup vs baseline: 1.4729x; 1.4729x over previous
//
#include <hip/hip_runtime.h>
#include <hip/hip_bf16.h>

#define B_ 2
#define S_ 4096
#define DM 512
#define NH 8
#define DK 64

typedef __bf16 bf16;
typedef __attribute__((ext_vector_type(8))) __bf16 bf16x8;
typedef __attribute__((ext_vector_type(4))) float f32x4;
typedef __attribute__((ext_vector_type(16))) float f32x16;

// Stage 16 consecutive fp32 -> 16 bf16 into a 128B LDS row with XOR block swizzle.
__device__ __forceinline__ void stage16f(const float* __restrict__ src,
                                         bf16* __restrict__ row, int half, int r) {
  const f32x4* s4 = (const f32x4*)src;
  f32x4 f0 = s4[0], f1 = s4[1], f2 = s4[2], f3 = s4[3];
  bf16x8 h0, h1;
#pragma unroll
  for (int i = 0; i < 4; ++i) {
    h0[i]     = (__bf16)f0[i];
    h0[4 + i] = (__bf16)f1[i];
    h1[i]     = (__bf16)f2[i];
    h1[4 + i] = (__bf16)f3[i];
  }
  *(bf16x8*)(row + ((((half * 2)    ) ^ (r & 7)) << 3)) = h0;
  *(bf16x8*)(row + ((((half * 2) + 1) ^ (r & 7)) << 3)) = h1;
}

// ---------------- input projections: Q/K/V = X @ W^T + b (bf16 out) ----------------
__global__ __launch_bounds__(256) void proj_in(
    const float* __restrict__ q, const float* __restrict__ k, const float* __restrict__ v,
    const float* __restrict__ Wq, const float* __restrict__ bq,
    const float* __restrict__ Wk, const float* __restrict__ bk,
    const float* __restrict__ Wv, const float* __restrict__ bv,
    bf16* __restrict__ Qh, bf16* __restrict__ Kh, bf16* __restrict__ Vt) {
  __shared__ bf16 Ash[128][64];
  __shared__ bf16 Bsh[128][64];

  const int mode = blockIdx.z;
  const float* X    = (mode == 0) ? q  : (mode == 1) ? k  : v;
  const float* W    = (mode == 0) ? Wq : (mode == 1) ? Wk : Wv;
  const float* bias = (mode == 0) ? bq : (mode == 1) ? bk : bv;

  const int t = threadIdx.x, wid = t >> 6, lane = t & 63;
  const int g = lane >> 4, lr = lane & 15;
  const int tileM = blockIdx.x * 128, tileN = blockIdx.y * 128;
  const int wr = (wid >> 1) * 64, wc = (wid & 1) * 64;
  const int sr = t >> 1, sc = (t & 1) * 16;

  f32x4 acc[4][4] = {};

  for (int k0 = 0; k0 < DM; k0 += 32) {
    stage16f(X + (size_t)(tileM + sr) * DM + k0 + sc, &Ash[sr][0], t & 1, sr);
    stage16f(W + (size_t)(tileN + sr) * DM + k0 + sc, &Bsh[sr][0], t & 1, sr);
    __syncthreads();
    bf16x8 af[4], bfr[4];
#pragma unroll
    for (int i = 0; i < 4; ++i) {
      int ra = wr + i * 16 + lr;
      af[i]  = *(const bf16x8*)(&Ash[ra][(g ^ (ra & 7)) << 3]);
      int rb = wc + i * 16 + lr;
      bfr[i] = *(const bf16x8*)(&Bsh[rb][(g ^ (rb & 7)) << 3]);
    }
#pragma unroll
    for (int i = 0; i < 4; ++i)
#pragma unroll
      for (int j = 0; j < 4; ++j)
        acc[i][j] = __builtin_amdgcn_mfma_f32_16x16x32_bf16(af[i], bfr[j], acc[i][j], 0, 0, 0);
    __syncthreads();
  }

  const float scale = (mode == 0) ? 0.125f : 1.0f;  // fold 1/sqrt(64) into Q
#pragma unroll
  for (int j = 0; j < 4; ++j) {
    int n = tileN + wc + j * 16 + lr;
    float bv_ = bias[n];
    int h = n >> 6, d = n & 63;
#pragma unroll
    for (int i = 0; i < 4; ++i) {
#pragma unroll
      for (int r = 0; r < 4; ++r) {
        int m = tileM + wr + i * 16 + g * 4 + r;
        int b = m >> 12, s = m & (S_ - 1);
        bf16 val = (__bf16)((acc[i][j][r] + bv_) * scale);
        if (mode == 2)
          Vt[((size_t)(b * NH + h) * DK + d) * S_ + s] = val;            // [b][h][d][s]
        else if (mode == 0)
          Qh[(((size_t)(b * NH + h) * S_ + s) << 6) + d] = val;          // [b][h][s][d]
        else
          Kh[(((size_t)(b * NH + h) * S_ + s) << 6) + d] = val;
      }
    }
  }
}

// ---------------- flash attention (swapped QK^T, 32x32 MFMA, in-register softmax) ----------------
__global__ __launch_bounds__(256) void attn_kernel(
    const bf16* __restrict__ Qh, const bf16* __restrict__ Kh,
    const bf16* __restrict__ Vt, bf16* __restrict__ O) {
  __shared__ bf16 Klds[2][64][64];   // [buf][kv][d]  (16B blocks XOR-swizzled by row&7)
  __shared__ bf16 Vlds[2][64][64];   // [buf][dv][kv] (same swizzle)

  const int t = threadIdx.x;
  const int lane = t & 63, wid = t >> 6;
  const int l31 = lane & 31, hi = lane >> 5;
  const int bh = blockIdx.y;
  const int q0 = blockIdx.x * 128 + wid * 32;

  const bf16* __restrict__ Qb = Qh + (size_t)bh * S_ * DK;
  const bf16* __restrict__ Kb = Kh + (size_t)bh * S_ * DK;
  const bf16* __restrict__ Vb = Vt + (size_t)bh * DK * S_;

  // Q fragments (B-operand of mfma(K,Q)): qf[s] holds Q[q0+l31][16s+8hi .. +7]
  bf16x8 qf[4];
#pragma unroll
  for (int s = 0; s < 4; ++s)
    qf[s] = *(const bf16x8*)(Qb + (size_t)(q0 + l31) * DK + s * 16 + hi * 8);

  // staging map: thread t covers rows r0 and r0+32, global 16B-block c0,
  // stored at swizzled LDS block (c0 ^ (r&7)).
  const int r0 = t >> 3;                 // 0..31
  const int c0 = t & 7;                  // global 16B block within 128B row
  const int bl0 = (c0 ^ (r0 & 7)) * 8;   // LDS element offset (row&7 same for r0+32)
  const int swz = l31 & 7;

  // prologue: stage tile 0 into buf 0
  *(bf16x8*)(&Klds[0][r0][bl0])      = *(const bf16x8*)(Kb + (size_t)r0 * DK + c0 * 8);
  *(bf16x8*)(&Klds[0][r0 + 32][bl0]) = *(const bf16x8*)(Kb + (size_t)(r0 + 32) * DK + c0 * 8);
  *(bf16x8*)(&Vlds[0][r0][bl0])      = *(const bf16x8*)(Vb + (size_t)r0 * S_ + c0 * 8);
  *(bf16x8*)(&Vlds[0][r0 + 32][bl0]) = *(const bf16x8*)(Vb + (size_t)(r0 + 32) * S_ + c0 * 8);
  __syncthreads();

  f32x16 oacc0 = {}, oacc1 = {};
  float ms = -__builtin_inff(), ls = 0.f;

  for (int kv0 = 0; kv0 < S_; kv0 += 64) {
    const int cur = (kv0 >> 6) & 1, nxt = cur ^ 1;
    const bool pre = (kv0 + 64) < S_;
    bf16x8 kst0, kst1, vst0, vst1;
    if (pre) {  // issue next-tile global loads early; latency hides under compute
      const int kvn = kv0 + 64;
      kst0 = *(const bf16x8*)(Kb + (size_t)(kvn + r0) * DK + c0 * 8);
      kst1 = *(const bf16x8*)(Kb + (size_t)(kvn + r0 + 32) * DK + c0 * 8);
      vst0 = *(const bf16x8*)(Vb + (size_t)r0 * S_ + kvn + c0 * 8);
      vst1 = *(const bf16x8*)(Vb + (size_t)(r0 + 32) * S_ + kvn + c0 * 8);
    }

    // ---- QK^T: sacc[kv][q] = mfma(A=K, B=Q); lane owns q-row l31 ----
    f32x16 s0 = {}, s1 = {};
#pragma unroll
    for (int s = 0; s < 4; ++s) {
      const int cb = ((2 * s + hi) ^ swz) * 8;
      bf16x8 kf0 = *(const bf16x8*)(&Klds[cur][l31][cb]);
      bf16x8 kf1 = *(const bf16x8*)(&Klds[cur][32 + l31][cb]);
      s0 = __builtin_amdgcn_mfma_f32_32x32x16_bf16(kf0, qf[s], s0, 0, 0, 0);
      s1 = __builtin_amdgcn_mfma_f32_32x32x16_bf16(kf1, qf[s], s1, 0, 0, 0);
    }

    // ---- online softmax, fully in-register (lane holds 32 of 64 kv for q=l31) ----
    float mx[16];
#pragma unroll
    for (int i = 0; i < 16; ++i) mx[i] = fmaxf(s0[i], s1[i]);
#pragma unroll
    for (int st = 8; st > 0; st >>= 1)
#pragma unroll
      for (int i = 0; i < st; ++i) mx[i] = fmaxf(mx[i], mx[i + st]);
    float mloc = fmaxf(mx[0], __shfl_xor(mx[0], 32));

    if (!__all(mloc <= ms + 8.f)) {  // defer-max (T13): skip rescale when growth <= 8
      float mnew = fmaxf(ms, mloc);
      float sf = __expf(ms - mnew);
      ms = mnew;
      ls *= sf;
#pragma unroll
      for (int i = 0; i < 16; ++i) { oacc0[i] *= sf; oacc1[i] *= sf; }
    }

    float p[32];
#pragma unroll
    for (int i = 0; i < 16; ++i) {
      p[i]      = __expf(s0[i] - ms);
      p[16 + i] = __expf(s1[i] - ms);
    }
    float sm[16];
#pragma unroll
    for (int i = 0; i < 16; ++i) sm[i] = p[i] + p[i + 16];
#pragma unroll
    for (int st = 8; st > 0; st >>= 1)
#pragma unroll
      for (int i = 0; i < st; ++i) sm[i] += sm[i + st];
    ls += sm[0] + __shfl_xor(sm[0], 32);

    // ---- P(f32) -> PV A-fragments (bf16) via cvt_pk + permlane32_swap (T12) ----
    bf16x8 pa[4];
#pragma unroll
    for (int gi = 0; gi < 4; ++gi) {
      unsigned wa, wb, wc_, wd;
      asm("v_cvt_pk_bf16_f32 %0, %1, %2" : "=v"(wa)  : "v"(p[gi*8+0]), "v"(p[gi*8+1]));
      asm("v_cvt_pk_bf16_f32 %0, %1, %2" : "=v"(wb)  : "v"(p[gi*8+4]), "v"(p[gi*8+5]));
      asm("v_cvt_pk_bf16_f32 %0, %1, %2" : "=v"(wc_) : "v"(p[gi*8+2]), "v"(p[gi*8+3]));
      asm("v_cvt_pk_bf16_f32 %0, %1, %2" : "=v"(wd)  : "v"(p[gi*8+6]), "v"(p[gi*8+7]));
      asm("v_permlane32_swap_b32 %0, %1" : "+v"(wa),  "+v"(wb));
      asm("v_permlane32_swap_b32 %0, %1" : "+v"(wc_), "+v"(wd));
      union { unsigned u[4]; bf16x8 v; } pk;
      pk.u[0] = wa; pk.u[1] = wc_; pk.u[2] = wb; pk.u[3] = wd;
      pa[gi] = pk.v;
    }

    // ---- PV: oacc[q][dv] += P[q][kv] * V[kv][dv]  (B from Vt rows) ----
#pragma unroll
    for (int ks = 0; ks < 4; ++ks) {
      const int cb = ((2 * ks + hi) ^ swz) * 8;
      bf16x8 vf0 = *(const bf16x8*)(&Vlds[cur][l31][cb]);
      bf16x8 vf1 = *(const bf16x8*)(&Vlds[cur][32 + l31][cb]);
      oacc0 = __builtin_amdgcn_mfma_f32_32x32x16_bf16(pa[ks], vf0, oacc0, 0, 0, 0);
      oacc1 = __builtin_amdgcn_mfma_f32_32x32x16_bf16(pa[ks], vf1, oacc1, 0, 0, 0);
    }

    if (pre) {  // write staged regs into the free buffer (vmcnt wait compiler-inserted)
      *(bf16x8*)(&Klds[nxt][r0][bl0])      = kst0;
      *(bf16x8*)(&Klds[nxt][r0 + 32][bl0]) = kst1;
      *(bf16x8*)(&Vlds[nxt][r0][bl0])      = vst0;
      *(bf16x8*)(&Vlds[nxt][r0 + 32][bl0]) = vst1;
    }
    __syncthreads();
  }

  // ---- epilogue: O[q][dv] = oacc / l ----
  bf16* __restrict__ Ob = O + ((size_t)bh * S_ + q0) * DK;
  float inv = 1.0f / ls;
#pragma unroll
  for (int r = 0; r < 16; ++r) {
    const int qq = (r & 3) + 8 * (r >> 2) + 4 * hi;   // C/D row mapping (m74/m101)
    float invr = __shfl(inv, qq);
    Ob[(size_t)qq * DK + l31]      = (__bf16)(oacc0[r] * invr);
    Ob[(size_t)qq * DK + 32 + l31] = (__bf16)(oacc1[r] * invr);
  }
}

// ---------------- output projection: out = concat(O) @ Wo^T + bo (fp32 out) ----------------
__global__ __launch_bounds__(256) void proj_out(
    const bf16* __restrict__ O, const float* __restrict__ Wo,
    const float* __restrict__ bo, float* __restrict__ out) {
  __shared__ bf16 Ash[128][64];
  __shared__ bf16 Bsh[128][64];

  const int t = threadIdx.x, wid = t >> 6, lane = t & 63;
  const int g = lane >> 4, lr = lane & 15;
  const int tileM = blockIdx.x * 128, tileN = blockIdx.y * 128;
  const int wr = (wid >> 1) * 64, wc = (wid & 1) * 64;
  const int sr = t >> 1, sc = (t & 1) * 16;

  f32x4 acc[4][4] = {};
  const int m0 = tileM + sr;
  const int bb = m0 >> 12, ss = m0 & (S_ - 1);

  for (int k0 = 0; k0 < DM; k0 += 32) {
    int kk = k0 + sc;
    int h = kk >> 6, d = kk & 63;
    const bf16* srcA = O + (((size_t)(bb * NH + h) * S_ + ss) << 6) + d;
    bf16x8 a0 = *(const bf16x8*)(srcA);
    bf16x8 a1 = *(const bf16x8*)(srcA + 8);
    *(bf16x8*)(&Ash[sr][((((t & 1) * 2)    ) ^ (sr & 7)) << 3]) = a0;
    *(bf16x8*)(&Ash[sr][((((t & 1) * 2) + 1) ^ (sr & 7)) << 3]) = a1;
    stage16f(Wo + (size_t)(tileN + sr) * DM + kk, &Bsh[sr][0], t & 1, sr);
    __syncthreads();
    bf16x8 af[4], bfr[4];
#pragma unroll
    for (int i = 0; i < 4; ++i) {
      int ra = wr + i * 16 + lr;
      af[i]  = *(const bf16x8*)(&Ash[ra][(g ^ (ra & 7)) << 3]);
      int rb = wc + i * 16 + lr;
      bfr[i] = *(const bf16x8*)(&Bsh[rb][(g ^ (rb & 7)) << 3]);
    }
#pragma unroll
    for (int i = 0; i < 4; ++i)
#pragma unroll
      for (int j = 0; j < 4; ++j)
        acc[i][j] = __builtin_amdgcn_mfma_f32_16x16x32_bf16(af[i], bfr[j], acc[i][j], 0, 0, 0);
    __syncthreads();
  }

#pragma unroll
  for (int j = 0; j < 4; ++j) {
    int n = tileN + wc + j * 16 + lr;
    float bias = bo[n];
#pragma unroll
    for (int i = 0; i < 4; ++i) {
#pragma unroll
      for (int r = 0; r < 4; ++r) {
        int m = tileM + wr + i * 16 + g * 4 + r;
        out[(size_t)m * DM + n] = acc[i][j][r] + bias;
      }
    }
  }
}

extern "C" void kernel_launch(void* const* d_in, const int* in_sizes, int n_in,
                              void* d_out, int out_size, void* d_ws, size_t ws_size,
                              hipStream_t stream) {
  const float* q  = (const float*)d_in[0];
  const float* k  = (const float*)d_in[1];
  const float* v  = (const float*)d_in[2];
  const float* Wq = (const float*)d_in[3];
  const float* bq = (const float*)d_in[4];
  const float* Wk = (const float*)d_in[5];
  const float* bk = (const float*)d_in[6];
  const float* Wv = (const float*)d_in[7];
  const float* bv = (const float*)d_in[8];
  const float* Wo = (const float*)d_in[9];
  const float* bo = (const float*)d_in[10];
  float* out = (float*)d_out;

  const size_t perTensor = (size_t)B_ * NH * S_ * DK;  // 4,194,304 elems
  bf16* Qh = (bf16*)d_ws;
  bf16* Kh = Qh + perTensor;
  bf16* Vt = Kh + perTensor;
  bf16* O  = Vt + perTensor;

  proj_in<<<dim3(64, 4, 3), 256, 0, stream>>>(q, k, v, Wq, bq, Wk, bk, Wv, bv, Qh, Kh, Vt);
  attn_kernel<<<dim3(S_ / 128, B_ * NH), 256, 0, stream>>>(Qh, Kh, Vt, O);
  proj_out<<<dim3(64, 4), 256, 0, stream>>>(O, Wo, bo, out);
}